// Round 6
// baseline (120.899 us; speedup 1.0000x reference)
//
#include <hip/hip_runtime.h>
#include <math.h>

#define B   8
#define S   256
#define NT  50
#define E   64
#define NTE (NT * E)
#define EPSF 1e-16f

#define NW        4                 // waves per block
#define NTHREADS  (64 * NW)
#define LL_BLOCKS (B * S / 2)       // 1024 blocks; rows (ih, S-1-ih)
#define IN_BLOCKS (B * NT)          // 400 blocks
#define G         8                 // software-pipeline group size

__device__ __forceinline__ float softplus(float x) {
    if (x > 20.0f) return x;
    return log1pf(__expf(x));
}

__device__ __forceinline__ float wave_reduce_sum(float v) {
    #pragma unroll
    for (int off = 32; off > 0; off >>= 1)
        v += __shfl_down(v, off, 64);
    return v;  // lane 0 holds the sum
}

// ---------------------------------------------------------------------------
// Load one group of G iterations into named register arrays.
// slot s = g*G+q, event j = w + s*NW (wrapped into s_ev bounds; out-of-range
// slots get A=P=0 so their contribution is exactly 0: exp(0)=1, fma(0,..)).
// All indices are compile-time after unroll -> arrays stay in VGPRs.
// ---------------------------------------------------------------------------
#define LOADG(g, TT, EE, AA, PP) do {                                       \
    _Pragma("unroll")                                                       \
    for (int q = 0; q < G; ++q) {                                           \
        const int s  = (g) * G + q;                                         \
        const int jj = (w + s * NW) & (S - 1);                              \
        const float4 ev = s_ev[jj];            /* uniform b128 broadcast */ \
        TT[q] = ev.x;                                                       \
        EE[q] = s_emb[__float_as_int(ev.y) + e];                            \
        const int  idx = __float_as_int(ev.z) + col;                        \
        const bool ok  = (s < scnt);           /* wave-uniform guard */     \
        AA[q] = ok ? Amat[idx] : 0.0f;                                      \
        PP[q] = ok ? Pmat[idx] : 0.0f;                                      \
    } } while (0)

#define COMPG_LL(TT, EE, AA, PP) do {                                       \
    _Pragma("unroll")                                                       \
    for (int q = 0; q < G; ++q) {                                           \
        const float dt = t_i - TT[q];                                       \
        const float ex = __expf(negEi * PP[q] * EE[q] * dt);                \
        if (q & 1) m1 = fmaf(AA[q] * EE[q], ex, m1);                        \
        else       m0 = fmaf(AA[q] * EE[q], ex, m0);                        \
    } } while (0)

#define COMPG_IN(TT, EE, AA, PP) do {                                       \
    _Pragma("unroll")                                                       \
    for (int q = 0; q < G; ++q) {                                           \
        const float dT = Tf - TT[q];                                        \
        const float ex = __expf(negEk * PP[q] * EE[q] * dT);                \
        const float c  = AA[q] * EE[q] * ex;                                \
        if (q & 1) a1 += (TT[q] >= 0.0f) ? c : 0.0f;                        \
        else       a0 += (TT[q] >= 0.0f) ? c : 0.0f;                        \
    } } while (0)

// ---------------------------------------------------------------------------
// Main kernel. Grid = LL_BLOCKS + IN_BLOCKS, 256 threads (4 waves).
// Double-buffered G=8 software pipeline: loads for group g+1 are issued
// before computing group g, so ~16 global loads + 16 LDS reads are in
// flight while the exp/fma chain runs. __launch_bounds__(256,3) gives the
// register allocator room (~168 VGPR cap) for the pipeline state.
// ---------------------------------------------------------------------------
__global__ __launch_bounds__(NTHREADS, 3) void main_kernel(
    const float* __restrict__ times, const int* __restrict__ types,
    const int* __restrict__ Tp,
    const float* __restrict__ emb,  const float* __restrict__ a,
    const float* __restrict__ Amat, const float* __restrict__ Pmat,
    float* __restrict__ ws_ll, float* __restrict__ ws_int)
{
    const int tid = threadIdx.x;
    const int e   = tid & 63;
    const int w   = tid >> 6;
    const int bid = blockIdx.x;
    const bool is_ll = (bid < LL_BLOCKS);
    const int b = is_ll ? (bid / (S / 2)) : ((bid - LL_BLOCKS) / NT);

    __shared__ __align__(16) float  s_emb[NTE];   // 12.8 KB
    __shared__ __align__(16) float4 s_ev[S];      // (t, ty*E, ty*NTE, 0) bits
    __shared__ float s_part[2][NW][E];
    __shared__ float s_row[2];

    {
        const float4* __restrict__ emb4 = (const float4*)emb;
        float4* s4 = (float4*)s_emb;
        for (int idx = tid; idx < NTE / 4; idx += NTHREADS)
            s4[idx] = emb4[idx];
    }
    for (int j = tid; j < S; j += NTHREADS) {
        const int ty = types[b * S + j];
        s_ev[j] = make_float4(times[b * S + j],
                              __int_as_float(ty * E),
                              __int_as_float(ty * NTE), 0.0f);
    }
    __syncthreads();

    if (is_ll) {
        const int ih = bid % (S / 2);
        const int rows[2] = { ih, S - 1 - ih };
        #pragma unroll
        for (int r = 0; r < 2; ++r) {
            const int   i     = rows[r];
            const float t_i   = s_ev[i].x;
            const int   col   = __float_as_int(s_ev[i].y) + e;  // tyi*E + e
            const float negEi = -s_emb[col];
            const int scnt = (i > w) ? ((i - w + NW - 1) / NW) : 0;
            const int ngp  = (scnt + G - 1) / G;                // <= 8

            float m0 = 0.0f, m1 = 0.0f;
            float TA[G], EA[G], Aa[G], PA[G];
            float TB[G], EB[G], Ab[G], PB[G];
            LOADG(0, TA, EA, Aa, PA);
            for (int g = 0; g < ngp; g += 2) {
                LOADG(g + 1, TB, EB, Ab, PB);
                COMPG_LL(TA, EA, Aa, PA);
                LOADG(g + 2, TA, EA, Aa, PA);
                COMPG_LL(TB, EB, Ab, PB);
            }
            s_part[r][w][e] = m0 + m1;
        }
        __syncthreads();
        if (w < 2) {
            const int   i     = rows[w];
            const float t_i   = s_ev[i].x;
            const int   col   = __float_as_int(s_ev[i].y) + e;
            const float emb_i = s_emb[col];
            float mt = 0.0f;
            #pragma unroll
            for (int q = 0; q < NW; ++q) mt += s_part[w][q][e];
            const float sp    = softplus(fmaf(emb_i, mt, emb_i * a[col]));
            const float inten = wave_reduce_sum(sp);
            if (e == 0)
                s_row[w] = (t_i >= 0.0f) ? logf(inten + EPSF) : 0.0f;
        }
        __syncthreads();
        if (tid == 0) ws_ll[bid] = s_row[0] + s_row[1];
    } else {
        const int   k     = (bid - LL_BLOCKS) % NT;
        const float Tf    = (float)(*Tp);
        const int   col   = k * E + e;
        const float embk  = s_emb[col];
        const float negEk = -embk;
        const int scnt = (S - w + NW - 1) / NW;   // 64
        const int ngp  = (scnt + G - 1) / G;      // 8 (even)

        float a0 = 0.0f, a1 = 0.0f;
        float TA[G], EA[G], Aa[G], PA[G];
        float TB[G], EB[G], Ab[G], PB[G];
        LOADG(0, TA, EA, Aa, PA);
        for (int g = 0; g < ngp; g += 2) {
            LOADG(g + 1, TB, EB, Ab, PB);
            COMPG_IN(TA, EA, Aa, PA);
            LOADG(g + 2, TA, EA, Aa, PA);
            COMPG_IN(TB, EB, Ab, PB);
        }
        s_part[0][w][e] = a0 + a1;
        __syncthreads();
        if (w == 0) {
            float mt = 0.0f;
            #pragma unroll
            for (int q = 0; q < NW; ++q) mt += s_part[0][q][e];
            const float sp = softplus(fmaf(embk, mt, embk * a[col]));
            const float ss = wave_reduce_sum(sp);
            if (e == 0) ws_int[bid - LL_BLOCKS] = ss;
        }
    }
}

// ---------------------------------------------------------------------------
// Finalize: one block, 4 waves (round-0 verified version).
// ---------------------------------------------------------------------------
__global__ __launch_bounds__(256) void finalize_kernel(
    const float* __restrict__ times,
    const int* __restrict__ Tp,
    const float* __restrict__ emb, const float* __restrict__ a,
    const float* __restrict__ ws_ll, const float* __restrict__ ws_int,
    float* __restrict__ out)
{
    const int t    = threadIdx.x;
    const int lane = t & 63;
    const int w    = t >> 6;
    const float Tf = (float)(*Tp);

    float llp = 0.0f;
    for (int idx = t; idx < LL_BLOCKS; idx += 256) llp += ws_ll[idx];
    float bs = 0.0f;
    for (int idx = t; idx < NTE; idx += 256) bs += softplus(emb[idx] * a[idx]);

    __shared__ float red[256], red2[256];
    red[t] = llp; red2[t] = bs;

    __shared__ float s_first[B], s_last[B], s_iT[B], s_any[B];
    for (int b = w; b < B; b += 4) {
        float mn = 1e30f, mx = -1e30f;
        #pragma unroll
        for (int q = 0; q < S / 64; ++q) {
            const float tv = times[b * S + q * 64 + lane];
            const bool valid = (tv >= 0.0f);
            mn = fminf(mn, valid ? tv : 1e30f);
            mx = fmaxf(mx, valid ? tv : -1e30f);
        }
        float iv = (lane < NT) ? ws_int[b * NT + lane] : 0.0f;
        #pragma unroll
        for (int off = 32; off > 0; off >>= 1) {
            mn = fminf(mn, __shfl_down(mn, off, 64));
            mx = fmaxf(mx, __shfl_down(mx, off, 64));
            iv += __shfl_down(iv, off, 64);
        }
        if (lane == 0) {
            const bool any_valid = (mn < 1e29f);
            s_any[b]   = any_valid ? 1.0f : 0.0f;
            s_first[b] = any_valid ? mn : 0.0f;
            s_last[b]  = any_valid ? mx : 0.0f;
            s_iT[b]    = iv;
        }
    }
    __syncthreads();

    for (int off = 128; off > 0; off >>= 1) {
        if (t < off) { red[t] += red[t + off]; red2[t] += red2[t + off]; }
        __syncthreads();
    }

    if (t == 0) {
        const float base_sum = red2[0];
        float integral = 0.0f;
        #pragma unroll
        for (int b = 0; b < B; ++b) {
            integral += (s_any[b] > 0.5f)
                ? s_iT[b] * (Tf - s_last[b]) + base_sum * s_first[b]
                : base_sum * Tf;
        }
        out[0] = integral - red[0];
    }
}

extern "C" void kernel_launch(void* const* d_in, const int* in_sizes, int n_in,
                              void* d_out, int out_size, void* d_ws, size_t ws_size,
                              hipStream_t stream) {
    const float* times = (const float*)d_in[0];
    const int*   types = (const int*)d_in[1];
    const int*   Tp    = (const int*)d_in[2];
    const float* emb   = (const float*)d_in[3];
    const float* a     = (const float*)d_in[4];
    const float* Amat  = (const float*)d_in[5];
    const float* Pmat  = (const float*)d_in[6];

    float* ws     = (float*)d_ws;
    float* ws_ll  = ws;                  // [0, 1024)
    float* ws_int = ws + LL_BLOCKS;      // [1024, 1424)
    float* out    = (float*)d_out;

    main_kernel<<<LL_BLOCKS + IN_BLOCKS, NTHREADS, 0, stream>>>(
        times, types, Tp, emb, a, Amat, Pmat, ws_ll, ws_int);
    finalize_kernel<<<1, 256, 0, stream>>>(times, Tp, emb, a, ws_ll, ws_int, out);
}

// Round 7
// 87.328 us; speedup vs baseline: 1.3844x; 1.3844x over previous
//
#include <hip/hip_runtime.h>
#include <math.h>

#define B   8
#define S   256
#define NT  50
#define E   64
#define NTE (NT * E)
#define EPSF 1e-16f

#define NW        8                 // waves per block (512 threads) -- TLP x2
#define NTHREADS  (64 * NW)
#define LL_BLOCKS (B * S / 2)       // 1024 blocks; each handles rows (ih, S-1-ih)
#define IN_BLOCKS (B * NT)          // 400 blocks

__device__ __forceinline__ float softplus(float x) {
    if (x > 20.0f) return x;
    return log1pf(__expf(x));
}

__device__ __forceinline__ float wave_reduce_sum(float v) {
    #pragma unroll
    for (int off = 32; off > 0; off >>= 1)
        v += __shfl_down(v, off, 64);
    return v;  // lane 0 holds the sum
}

// ---------------------------------------------------------------------------
// Main kernel. Grid = LL_BLOCKS + IN_BLOCKS, 512 threads (8 waves).
//
// Round-0 verified body; the ONLY structural change is NW 4 -> 8: each row's
// j-loop splits across 8 waves (~32 iters/wave), doubling machine-wide wave
// count to ~11.1/SIMD so the ~450-cycle ds_read->global-load chain is hidden
// by TLP instead of (spill-prone) register pipelining. __launch_bounds__
// (512,8) caps VGPR at 64 -> 4 blocks/CU (32 waves/CU) resident.
//
// LL blocks: batch b, row pair (ih, 255-ih) -> uniform 255 inner iters/block.
// Integral blocks: (b,k); invalid events predicated out.
// ---------------------------------------------------------------------------
__global__ __launch_bounds__(NTHREADS, 8) void main_kernel(
    const float* __restrict__ times, const int* __restrict__ types,
    const int* __restrict__ Tp,
    const float* __restrict__ emb,  const float* __restrict__ a,
    const float* __restrict__ Amat, const float* __restrict__ Pmat,
    float* __restrict__ ws_ll, float* __restrict__ ws_int)
{
    const int tid = threadIdx.x;
    const int e   = tid & 63;
    const int w   = tid >> 6;
    const int bid = blockIdx.x;
    const bool is_ll = (bid < LL_BLOCKS);
    const int b = is_ll ? (bid / (S / 2)) : ((bid - LL_BLOCKS) / NT);

    __shared__ __align__(16) float  s_emb[NTE];   // 12.8 KB, lane-contiguous
    __shared__ __align__(16) float4 s_ev[S];      // (t, ty*E, ty*NTE, 0) bits
    __shared__ float s_part[2][NW][E];            // 4 KB
    __shared__ float s_row[2];

    {
        const float4* __restrict__ emb4 = (const float4*)emb;
        float4* s4 = (float4*)s_emb;
        for (int idx = tid; idx < NTE / 4; idx += NTHREADS)
            s4[idx] = emb4[idx];
    }
    for (int j = tid; j < S; j += NTHREADS) {
        const int ty = types[b * S + j];
        s_ev[j] = make_float4(times[b * S + j],
                              __int_as_float(ty * E),
                              __int_as_float(ty * NTE), 0.0f);
    }
    __syncthreads();

    if (is_ll) {
        const int ih = bid % (S / 2);
        const int rows[2] = { ih, S - 1 - ih };
        #pragma unroll
        for (int r = 0; r < 2; ++r) {
            const int   i     = rows[r];
            const float t_i   = s_ev[i].x;
            const int   col   = __float_as_int(s_ev[i].y) + e;   // tyi*E + e
            const float negEi = -s_emb[col];

            float macc = 0.0f;
            #pragma unroll 8
            for (int j = w; j < i; j += NW) {
                const float4 ev  = s_ev[j];                      // uniform b128
                const float  dtj = t_i - ev.x;
                const int   base = __float_as_int(ev.z) + col;   // tyj*NTE+col
                const float ej   = s_emb[__float_as_int(ev.y) + e];
                const float Pe   = Pmat[base];
                const float Ae   = Amat[base];
                macc = fmaf(Ae * ej, __expf(negEi * Pe * ej * dtj), macc);
            }
            s_part[r][w][e] = macc;
        }
        __syncthreads();
        if (w < 2) {
            const int   i     = rows[w];
            const float t_i   = s_ev[i].x;
            const int   col   = __float_as_int(s_ev[i].y) + e;
            const float emb_i = s_emb[col];
            float mt = 0.0f;
            #pragma unroll
            for (int q = 0; q < NW; ++q) mt += s_part[w][q][e];
            const float sp    = softplus(fmaf(emb_i, mt, emb_i * a[col]));
            const float inten = wave_reduce_sum(sp);
            if (e == 0)
                s_row[w] = (t_i >= 0.0f) ? logf(inten + EPSF) : 0.0f;
        }
        __syncthreads();
        if (tid == 0) ws_ll[bid] = s_row[0] + s_row[1];
    } else {
        const int   k     = (bid - LL_BLOCKS) % NT;
        const float Tf    = (float)(*Tp);
        const int   colk  = k * E + e;
        const float embk  = s_emb[colk];
        const float negEk = -embk;

        float acc = 0.0f;
        #pragma unroll 8
        for (int i = w; i < S; i += NW) {
            const float4 ev  = s_ev[i];
            const float  dT  = Tf - ev.x;
            const int   base = __float_as_int(ev.z) + colk;
            const float et   = s_emb[__float_as_int(ev.y) + e];
            const float c    = Amat[base] * et * __expf(negEk * Pmat[base] * et * dT);
            acc += (ev.x >= 0.0f) ? c : 0.0f;   // predicated, no branch
        }
        s_part[0][w][e] = acc;
        __syncthreads();
        if (w == 0) {
            float mt = 0.0f;
            #pragma unroll
            for (int q = 0; q < NW; ++q) mt += s_part[0][q][e];
            const float sp = softplus(fmaf(embk, mt, embk * a[colk]));
            const float s  = wave_reduce_sum(sp);
            if (e == 0) ws_int[bid - LL_BLOCKS] = s;
        }
    }
}

// ---------------------------------------------------------------------------
// Finalize: one block, 4 waves (round-0 verified version, unchanged).
// ---------------------------------------------------------------------------
__global__ __launch_bounds__(256) void finalize_kernel(
    const float* __restrict__ times,
    const int* __restrict__ Tp,
    const float* __restrict__ emb, const float* __restrict__ a,
    const float* __restrict__ ws_ll, const float* __restrict__ ws_int,
    float* __restrict__ out)
{
    const int t    = threadIdx.x;
    const int lane = t & 63;
    const int w    = t >> 6;
    const float Tf = (float)(*Tp);

    float llp = 0.0f;
    for (int idx = t; idx < LL_BLOCKS; idx += 256) llp += ws_ll[idx];
    float bs = 0.0f;
    for (int idx = t; idx < NTE; idx += 256) bs += softplus(emb[idx] * a[idx]);

    __shared__ float red[256], red2[256];
    red[t] = llp; red2[t] = bs;

    __shared__ float s_first[B], s_last[B], s_iT[B], s_any[B];
    for (int b = w; b < B; b += 4) {
        float mn = 1e30f, mx = -1e30f;
        #pragma unroll
        for (int q = 0; q < S / 64; ++q) {
            const float tv = times[b * S + q * 64 + lane];
            const bool valid = (tv >= 0.0f);
            mn = fminf(mn, valid ? tv : 1e30f);
            mx = fmaxf(mx, valid ? tv : -1e30f);
        }
        float iv = (lane < NT) ? ws_int[b * NT + lane] : 0.0f;
        #pragma unroll
        for (int off = 32; off > 0; off >>= 1) {
            mn = fminf(mn, __shfl_down(mn, off, 64));
            mx = fmaxf(mx, __shfl_down(mx, off, 64));
            iv += __shfl_down(iv, off, 64);
        }
        if (lane == 0) {
            const bool any_valid = (mn < 1e29f);
            s_any[b]   = any_valid ? 1.0f : 0.0f;
            s_first[b] = any_valid ? mn : 0.0f;
            s_last[b]  = any_valid ? mx : 0.0f;
            s_iT[b]    = iv;
        }
    }
    __syncthreads();

    for (int off = 128; off > 0; off >>= 1) {
        if (t < off) { red[t] += red[t + off]; red2[t] += red2[t + off]; }
        __syncthreads();
    }

    if (t == 0) {
        const float base_sum = red2[0];
        float integral = 0.0f;
        #pragma unroll
        for (int b = 0; b < B; ++b) {
            integral += (s_any[b] > 0.5f)
                ? s_iT[b] * (Tf - s_last[b]) + base_sum * s_first[b]
                : base_sum * Tf;
        }
        out[0] = integral - red[0];
    }
}

extern "C" void kernel_launch(void* const* d_in, const int* in_sizes, int n_in,
                              void* d_out, int out_size, void* d_ws, size_t ws_size,
                              hipStream_t stream) {
    const float* times = (const float*)d_in[0];
    const int*   types = (const int*)d_in[1];
    const int*   Tp    = (const int*)d_in[2];
    const float* emb   = (const float*)d_in[3];
    const float* a     = (const float*)d_in[4];
    const float* Amat  = (const float*)d_in[5];
    const float* Pmat  = (const float*)d_in[6];

    float* ws     = (float*)d_ws;
    float* ws_ll  = ws;                  // [0, 1024)
    float* ws_int = ws + LL_BLOCKS;      // [1024, 1424)
    float* out    = (float*)d_out;

    main_kernel<<<LL_BLOCKS + IN_BLOCKS, NTHREADS, 0, stream>>>(
        times, types, Tp, emb, a, Amat, Pmat, ws_ll, ws_int);
    finalize_kernel<<<1, 256, 0, stream>>>(times, Tp, emb, a, ws_ll, ws_int, out);
}